// Round 1
// baseline (303.168 us; speedup 1.0000x reference)
//
#include <hip/hip_runtime.h>
#include <math.h>

#define N 256
#define PSTR 257  // partial-buffer stride (257 = 256+1 -> 2-way bank alias, free)

// One workgroup (1024 threads) per problem. Thread grid 32x32: thread (ti,tj)
// owns the 8x8 fp32 tile A[ti*8 .. +8][tj*8 .. +8] in VGPRs (64 regs) so the
// 256KB matrix is read from HBM exactly once per problem.
// Reductions (rows for A*x, cols for A^T*r) go through one padded LDS buffer.

__global__ __launch_bounds__(1024) void icvp_kernel(
    const float* __restrict__ X, const float* __restrict__ A,
    const float* __restrict__ Bv, float* __restrict__ out)
{
  const int p  = blockIdx.x;
  const int t  = threadIdx.x;
  const int ti = t >> 5;
  const int tj = t & 31;
  const bool rdr = (t < 256);          // reader / epilogue role: first 4 waves
  const int rk = t & 31;               // reader sub-indices
  const int rc = (t >> 5) & 7;
  const int ridx = rk * 8 + rc;        // reader's row (or col) index, bijective on [0,256)
  const int w  = t >> 6;

  __shared__ __align__(16) float part[8224];   // [32][PSTR] padded partial buffer
  __shared__ __align__(16) float xn[256];      // current x (normal layout)
  __shared__ __align__(16) float x0n[256];     // original x
  __shared__ __align__(16) float dn[256];      // AtAv temp, later d = x0 - x_uvp
  __shared__ __align__(16) float rn[256];      // row-space vector (Av / relu residual)
  __shared__ __align__(16) float invn[256];    // 1/row_norm
  __shared__ float btp[256];                   // b_tight, reader-planar [rc*32+rk]
  __shared__ float bwp[256];                   // b_w,     reader-planar
  __shared__ float scal[12];

  // ---- load A tile (coalesced: 2KB per wave-instruction) ----
  float Areg[8][8];
  {
    const float* Ap = A + (size_t)p * (N * N);
    #pragma unroll
    for (int r = 0; r < 8; ++r) {
      const float4* src = reinterpret_cast<const float4*>(Ap + (ti * 8 + r) * N + tj * 8);
      float4 a0 = src[0];
      float4 a1 = src[1];
      Areg[r][0] = a0.x; Areg[r][1] = a0.y; Areg[r][2] = a0.z; Areg[r][3] = a0.w;
      Areg[r][4] = a1.x; Areg[r][5] = a1.y; Areg[r][6] = a1.z; Areg[r][7] = a1.w;
    }
  }
  float b_raw = 0.f;
  if (rdr) {
    float xv = X[p * N + t];
    xn[t]  = xv;
    x0n[t] = xv;
    b_raw  = Bv[p * N + ridx];
  }

  // ---- helpers ----
  auto fwd_store = [&](const float (&vl)[8]) {   // partials of A*v, store [tj][r][ti]
    #pragma unroll
    for (int r = 0; r < 8; ++r) {
      float s = 0.f;
      #pragma unroll
      for (int c = 0; c < 8; ++c) s = fmaf(Areg[r][c], vl[c], s);
      part[tj * PSTR + r * 32 + ti] = s;
    }
  };
  auto trans_store = [&](const float (&rl)[8]) { // partials of A^T*r, store [ti][c][tj]
    #pragma unroll
    for (int c = 0; c < 8; ++c) {
      float s = 0.f;
      #pragma unroll
      for (int r = 0; r < 8; ++r) s = fmaf(Areg[r][c], rl[r], s);
      part[ti * PSTR + c * 32 + tj] = s;
    }
  };
  auto red32 = [&]() {   // reader: sum 32 partials for its row/col (2-way alias: free)
    float s0 = 0.f, s1 = 0.f, s2 = 0.f, s3 = 0.f;
    const int off = rc * 32 + rk;
    #pragma unroll
    for (int q = 0; q < 8; ++q) {
      s0 += part[(4 * q + 0) * PSTR + off];
      s1 += part[(4 * q + 1) * PSTR + off];
      s2 += part[(4 * q + 2) * PSTR + off];
      s3 += part[(4 * q + 3) * PSTR + off];
    }
    return (s0 + s1) + (s2 + s3);
  };
  auto load8 = [&](const float* base, float (&dst)[8], int idx8) {
    const float4* v4 = reinterpret_cast<const float4*>(base + idx8 * 8);
    float4 a0 = v4[0], a1 = v4[1];
    dst[0] = a0.x; dst[1] = a0.y; dst[2] = a0.z; dst[3] = a0.w;
    dst[4] = a1.x; dst[5] = a1.y; dst[6] = a1.z; dst[7] = a1.w;
  };

  // ---- row norms; scale A -> A_w; b_w, b_tight ----
  #pragma unroll
  for (int r = 0; r < 8; ++r) {
    float s = 0.f;
    #pragma unroll
    for (int c = 0; c < 8; ++c) s = fmaf(Areg[r][c], Areg[r][c], s);
    part[tj * PSTR + r * 32 + ti] = s;
  }
  __syncthreads();
  if (rdr) {
    float s = red32();
    float nrm = fmaxf(sqrtf(s), 1e-12f);
    float inv = 1.0f / nrm;
    invn[ridx] = inv;
    float bw = b_raw * inv;
    bwp[rc * 32 + rk] = bw;
    btp[rc * 32 + rk] = bw - 1e-3f;   // MU_INSIDE
  }
  __syncthreads();
  {
    float invl[8];
    load8(invn, invl, ti);
    #pragma unroll
    for (int r = 0; r < 8; ++r)
      #pragma unroll
      for (int c = 0; c < 8; ++c) Areg[r][c] *= invl[r];
  }

  // ---- power iteration (5 iters) for eta ----
  float vloc[8];
  #pragma unroll
  for (int c = 0; c < 8; ++c) vloc[c] = 0.0625f;   // ones/||ones||, exact

  for (int pit = 0; pit < 5; ++pit) {
    fwd_store(vloc);
    __syncthreads();
    if (rdr) rn[ridx] = red32();          // Av
    __syncthreads();
    float rl[8];
    load8(rn, rl, ti);
    trans_store(rl);
    __syncthreads();
    if (rdr) {
      float g = red32();                  // AtAv
      dn[ridx] = g;
      float ss = g * g;
      #pragma unroll
      for (int m = 1; m < 64; m <<= 1) ss += __shfl_xor(ss, m);
      if ((t & 63) == 0) scal[4 + w] = ss;
    }
    __syncthreads();
    if (t == 0) {
      float s = scal[4] + scal[5] + scal[6] + scal[7];
      scal[0] = sqrtf(s) + 1e-12f;        // denom = ||AtAv|| + 1e-12
    }
    __syncthreads();
    {
      float dl[8];
      load8(dn, dl, tj);
      float den = scal[0];
      #pragma unroll
      for (int c = 0; c < 8; ++c) vloc[c] = dl[c] / den;
    }
  }
  // eta = 1/(sum((A v)^2) + rho)
  fwd_store(vloc);
  __syncthreads();
  if (rdr) {
    float av = red32();
    float ss = av * av;
    #pragma unroll
    for (int m = 1; m < 64; m <<= 1) ss += __shfl_xor(ss, m);
    if ((t & 63) == 0) scal[4 + w] = ss;
  }
  __syncthreads();
  if (t == 0) scal[1] = 1.0f / (scal[4] + scal[5] + scal[6] + scal[7] + 1e-12f);
  __syncthreads();
  const float eta = scal[1];

  // ---- UVP: 30 iterations of x -= eta * A^T relu(A x - b_tight) ----
  float xloc[8];
  load8(xn, xloc, tj);
  for (int k = 0; k < 30; ++k) {
    fwd_store(xloc);
    __syncthreads();
    if (rdr) {
      float y = red32();
      rn[ridx] = fmaxf(y - btp[rc * 32 + rk], 0.f);
    }
    __syncthreads();
    float rl[8];
    load8(rn, rl, ti);
    trans_store(rl);
    __syncthreads();
    if (rdr) {
      float g = red32();
      xn[ridx] -= eta * g;
    }
    __syncthreads();
    load8(xn, xloc, tj);
  }

  // ---- stage 2: feasibility gate + alpha line search ----
  fwd_store(xloc);                         // A x_uvp
  __syncthreads();
  float slack = 0.f;
  if (rdr) {
    float ax = red32();
    float bw = bwp[rc * 32 + rk];
    slack = bw - ax;
    float mv = fmaxf(ax - bw, 0.f);
    #pragma unroll
    for (int m = 1; m < 64; m <<= 1) mv = fmaxf(mv, __shfl_xor(mv, m));
    if ((t & 63) == 0) scal[4 + w] = mv;
    dn[ridx] = x0n[ridx] - xn[ridx];       // d = x - x_uvp
  }
  __syncthreads();
  if (t == 0) scal[2] = fmaxf(fmaxf(scal[4], scal[5]), fmaxf(scal[6], scal[7]));
  __syncthreads();
  float dloc[8];
  load8(dn, dloc, tj);
  fwd_store(dloc);                         // A d
  __syncthreads();
  if (rdr) {
    float ad = red32();
    float ai = (ad > 0.f) ? slack / (ad + 1e-12f) : INFINITY;
    #pragma unroll
    for (int m = 1; m < 64; m <<= 1) ai = fminf(ai, __shfl_xor(ai, m));
    if ((t & 63) == 0) scal[8 + w] = ai;
  }
  __syncthreads();
  if (t == 0) {
    float al = fminf(fminf(scal[8], scal[9]), fminf(scal[10], scal[11]));
    if (!isfinite(al)) al = 1.0f;
    al = fminf(fmaxf(al - 1e-6f, 0.f), 1.0f);
    scal[3] = al;
  }
  __syncthreads();
  if (rdr) {
    float alpha = scal[3];
    bool da = (scal[2] <= 1e-7f);          // max_viol <= ALPHA_FEAS_TOL
    float xv = xn[t];
    out[p * N + t] = da ? fmaf(alpha, dn[t], xv) : xv;
  }
}

extern "C" void kernel_launch(void* const* d_in, const int* in_sizes, int n_in,
                              void* d_out, int out_size, void* d_ws, size_t ws_size,
                              hipStream_t stream) {
  const float* X  = (const float*)d_in[0];
  const float* A  = (const float*)d_in[1];
  const float* Bv = (const float*)d_in[2];
  float* out = (float*)d_out;
  const int nprob = in_sizes[0] / N;       // 512
  icvp_kernel<<<nprob, 1024, 0, stream>>>(X, A, Bv, out);
}